// Round 2
// baseline (148.712 us; speedup 1.0000x reference)
//
#include <hip/hip_runtime.h>
#include <hip/hip_cooperative_groups.h>
#include <math.h>

namespace cg = cooperative_groups;

namespace {
constexpr int kB = 32;
constexpr int kH = 38;
constexpr int kW = 38;
constexpr int kA = 5;
constexpr int kC = 80;
constexpr int kT = 60;
constexpr int kHW = kH * kW;                           // 1444
constexpr int kCellsPerB = kHW * kA;                   // 7220
constexpr int kChan = 5 + kC;                          // 85
constexpr int kMainBlocks = (kCellsPerB + 255) / 256;  // 29
constexpr int kNPart = kMainBlocks * kB;               // 928
constexpr float kThresh = 0.6f;
constexpr int kPriorIter = 12800;
}

// One fused kernel: per-truth target precompute (staging threads), per-cell
// noobj test + winner scan + all loss terms, block reduce, grid sync, final
// deterministic reduce by block (0,0). No atomics anywhere -> deterministic.
__global__ __launch_bounds__(256) void yolo_fused_kernel(
    const float* __restrict__ output,
    const float* __restrict__ truths,
    const float* __restrict__ anchors,
    const int* __restrict__ iter_p,
    float* __restrict__ partial,
    float* __restrict__ out) {
  const int b = blockIdx.y;
  const int idx = blockIdx.x * 256 + threadIdx.x;  // cell index within batch

  __shared__ float4 sbox[kT];   // x1,y1,x2,y2
  __shared__ float4 smeta[kT];  // area, best_anchor_iou, key(bitcast), pad
  __shared__ float4 stgt[kT];   // ddx, ddy, wh0, wh1
  __shared__ float2 sfxc[kT];   // fix^2, cls(bitcast int)
  __shared__ float sanch[2 * kA];
  __shared__ float rs[256];
  __shared__ float wsum[4];

  if (threadIdx.x < 2 * kA) sanch[threadIdx.x] = anchors[threadIdx.x];

  if (threadIdx.x < kT) {
    const int t = threadIdx.x;
    const float* tr = truths + (size_t)(b * kT + t) * 5;
    const float x1 = tr[0], y1 = tr[1], x2 = tr[2], y2 = tr[3], cls = tr[4];
    const float tw = x2 - x1, th = y2 - y1, tarea = tw * th;
    sbox[t] = make_float4(x1, y1, x2, y2);
    const float tdx = (x1 + x2) * 0.5f * (float)kW;
    const float tdy = (y1 + y2) * 0.5f * (float)kH;
    const float cxf = ceilf(tdx), cyf = ceilf(tdy);
    int gxi = (int)cxf - 1, gyi = (int)cyf - 1;
    gxi = min(max(gxi, 0), kW - 1);
    gyi = min(max(gyi, 0), kH - 1);
    // best anchor by truth-vs-anchor IoU (argmax, first on ties via strict >)
    float best = -1.0f;
    int ba = 0;
    for (int a2 = 0; a2 < kA; ++a2) {
      const float aw = anchors[2 * a2], ah = anchors[2 * a2 + 1];
      const float inter = fminf(tw, aw) * fminf(th, ah);
      const float uni = fmaxf(tarea + aw * ah - inter, 1e-12f);
      const float iou = inter / uni;
      if (iou > best) { best = iou; ba = a2; }
    }
    const int key = (gyi * kW + gxi) * kA + ba;
    smeta[t] = make_float4(tarea, best, __int_as_float(key), 0.0f);
    const float fxr = tdx - (cxf - 1.0f);
    const float fyr = tdy - (cyf - 1.0f);
    stgt[t] = make_float4(-logf(1.0f / fxr - 1.0f),
                          -logf(1.0f / fyr - 1.0f),
                          logf(tw) / anchors[2 * ba],
                          logf(th) / anchors[2 * ba + 1]);
    sfxc[t] = make_float2(2.0f - tarea, __int_as_float((int)cls));
  }
  __syncthreads();

  const bool priorOn = (*iter_p < kPriorIter);
  float contrib = 0.0f;

  if (idx < kCellsPerB) {
    const int hw = idx / kA;
    const int a = idx - hw * kA;
    const int gx = hw % kW;
    const int gy = hw / kW;
    const float* p = output + (size_t)(b * kCellsPerB + idx) * kChan;
    const float t0 = p[0], t1 = p[1], t2 = p[2], t3 = p[3], t4 = p[4];
    const float aw = sanch[2 * a], ah = sanch[2 * a + 1];

    const float sx = 1.0f / (1.0f + expf(-t0));
    const float sy = 1.0f / (1.0f + expf(-t1));
    const float cx = (sx + (float)gx) * (1.0f / (float)kW);
    const float cy = (sy + (float)gy) * (1.0f / (float)kH);
    const float pw = expf(t2) * aw;
    const float ph = expf(t3) * ah;
    const float px1 = cx - pw * 0.5f, px2 = cx + pw * 0.5f;
    const float py1 = cy - ph * 0.5f, py2 = cy + ph * 0.5f;
    const float parea = (px2 - px1) * (py2 - py1);

    // fused: noobj candidacy (max IoU < 0.6  <=>  all inter < 0.6*union)
    //      + winner scan (key match, max anchor-iou, first-t tiebreak)
    bool okno = true;
    int bt = -1;
    float bi = 0.0f;  // init 0 enforces reference's iou > 0 win condition
    for (int t = 0; t < kT; ++t) {
      const float4 bx = sbox[t];
      const float4 mt = smeta[t];
      const float xm = fmaxf(px1, bx.x), xM = fminf(px2, bx.z);
      const float ym = fmaxf(py1, bx.y), yM = fminf(py2, bx.w);
      const float inter = fmaxf(xM - xm, 0.0f) * fmaxf(yM - ym, 0.0f);
      const float uni = fmaxf(parea + mt.x - inter, 1e-12f);
      okno = okno && (inter < kThresh * uni);
      if (__float_as_int(mt.z) == idx && mt.y > bi) { bi = mt.y; bt = t; }
    }

    if (priorOn) {
      const float dw = pw - aw, dh = ph - ah;
      contrib += dw * dw + dh * dh;  // PRIOR_RATE = 1
    }

    if (bt >= 0) {
      const float4 tg = stgt[bt];
      const float2 fc = sfxc[bt];
      const float d0 = t0 - tg.x, d1 = t1 - tg.y;
      const float d2 = t2 - tg.z, d3 = t3 - tg.w;
      contrib += fc.x * (d0 * d0 + d1 * d1 + d2 * d2 + d3 * d3);  // COORD
      const float dob = t4 - bi;
      contrib += 5.0f * dob * dob;                                // OBJECT
      const int cls = __float_as_int(fc.y);
      float cs = 0.0f;
      for (int c = 0; c < kC; ++c) {
        const float d = p[5 + c] - ((c == cls) ? 1.0f : 0.0f);
        cs += d * d;
      }
      contrib += cs;                                              // CLASS
    } else if (okno) {
      contrib += t4 * t4;                                         // NOOBJ
    }
  }

  // deterministic block reduction
  for (int off = 32; off > 0; off >>= 1) contrib += __shfl_down(contrib, off);
  const int lane = threadIdx.x & 63;
  const int wid = threadIdx.x >> 6;
  if (lane == 0) wsum[wid] = contrib;
  __syncthreads();
  if (threadIdx.x == 0) {
    partial[b * kMainBlocks + blockIdx.x] = wsum[0] + wsum[1] + wsum[2] + wsum[3];
    __threadfence();
  }

  cg::this_grid().sync();

  if (blockIdx.x == 0 && blockIdx.y == 0) {
    float v = 0.0f;
    for (int i = threadIdx.x; i < kNPart; i += 256) v += partial[i];
    rs[threadIdx.x] = v;
    __syncthreads();
    for (int off = 128; off > 0; off >>= 1) {
      if (threadIdx.x < off) rs[threadIdx.x] += rs[threadIdx.x + off];
      __syncthreads();
    }
    if (threadIdx.x == 0) out[0] = rs[0] * (1.0f / (float)kB);
  }
}

extern "C" void kernel_launch(void* const* d_in, const int* in_sizes, int n_in,
                              void* d_out, int out_size, void* d_ws, size_t ws_size,
                              hipStream_t stream) {
  const float* output  = (const float*)d_in[0];
  const float* truths  = (const float*)d_in[1];
  const float* anchors = (const float*)d_in[2];
  const int*   iter_p  = (const int*)d_in[3];
  float* out = (float*)d_out;
  float* partial = (float*)d_ws;  // kNPart floats

  void* args[] = {(void*)&output, (void*)&truths, (void*)&anchors,
                  (void*)&iter_p, (void*)&partial, (void*)&out};
  hipLaunchCooperativeKernel((void*)yolo_fused_kernel, dim3(kMainBlocks, kB),
                             dim3(256), args, 0, stream);
}

// Round 3
// 22.754 us; speedup vs baseline: 6.5356x; 6.5356x over previous
//
#include <hip/hip_runtime.h>
#include <math.h>

namespace {
constexpr int kB = 32;
constexpr int kH = 38;
constexpr int kW = 38;
constexpr int kA = 5;
constexpr int kC = 80;
constexpr int kT = 60;
constexpr int kHW = kH * kW;                           // 1444
constexpr int kCellsPerB = kHW * kA;                   // 7220
constexpr int kChan = 5 + kC;                          // 85
constexpr int kMainBlocks = (kCellsPerB + 255) / 256;  // 29
constexpr int kNPart = kMainBlocks * kB;               // 928
constexpr float kThresh = 0.6f;
constexpr int kPriorIter = 12800;
}

// Main kernel: per-block truth staging + target precompute, per-cell noobj
// test fused with winner scan, all five loss terms, deterministic block
// reduction -> one partial per block. No atomics, no grid sync.
__global__ __launch_bounds__(256) void yolo_main_kernel(
    const float* __restrict__ output,
    const float* __restrict__ truths,
    const float* __restrict__ anchors,
    const int* __restrict__ iter_p,
    float* __restrict__ partial) {
  const int b = blockIdx.y;
  const int idx = blockIdx.x * 256 + threadIdx.x;  // cell index within batch

  __shared__ float4 sbox[kT];   // x1,y1,x2,y2
  __shared__ float4 smeta[kT];  // area, best_anchor_iou, key(bitcast), pad
  __shared__ float4 stgt[kT];   // ddx, ddy, wh0, wh1
  __shared__ float2 sfxc[kT];   // fix^2, cls(bitcast int)
  __shared__ float sanch[2 * kA];
  __shared__ float wsum[4];

  if (threadIdx.x < 2 * kA) sanch[threadIdx.x] = anchors[threadIdx.x];

  if (threadIdx.x < kT) {
    const int t = threadIdx.x;
    const float* tr = truths + (size_t)(b * kT + t) * 5;
    const float x1 = tr[0], y1 = tr[1], x2 = tr[2], y2 = tr[3], cls = tr[4];
    const float tw = x2 - x1, th = y2 - y1, tarea = tw * th;
    sbox[t] = make_float4(x1, y1, x2, y2);
    const float tdx = (x1 + x2) * 0.5f * (float)kW;
    const float tdy = (y1 + y2) * 0.5f * (float)kH;
    const float cxf = ceilf(tdx), cyf = ceilf(tdy);
    int gxi = (int)cxf - 1, gyi = (int)cyf - 1;
    gxi = min(max(gxi, 0), kW - 1);
    gyi = min(max(gyi, 0), kH - 1);
    // best anchor by truth-vs-anchor IoU (argmax, first on ties via strict >)
    float best = -1.0f;
    int ba = 0;
    for (int a2 = 0; a2 < kA; ++a2) {
      const float aw = anchors[2 * a2], ah = anchors[2 * a2 + 1];
      const float inter = fminf(tw, aw) * fminf(th, ah);
      const float uni = fmaxf(tarea + aw * ah - inter, 1e-12f);
      const float iou = inter / uni;
      if (iou > best) { best = iou; ba = a2; }
    }
    const int key = (gyi * kW + gxi) * kA + ba;
    smeta[t] = make_float4(tarea, best, __int_as_float(key), 0.0f);
    const float fxr = tdx - (cxf - 1.0f);
    const float fyr = tdy - (cyf - 1.0f);
    stgt[t] = make_float4(-logf(1.0f / fxr - 1.0f),
                          -logf(1.0f / fyr - 1.0f),
                          logf(tw) / anchors[2 * ba],
                          logf(th) / anchors[2 * ba + 1]);
    sfxc[t] = make_float2(2.0f - tarea, __int_as_float((int)cls));
  }
  __syncthreads();

  const bool priorOn = (*iter_p < kPriorIter);
  float contrib = 0.0f;

  if (idx < kCellsPerB) {
    const int hw = idx / kA;
    const int a = idx - hw * kA;
    const int gx = hw % kW;
    const int gy = hw / kW;
    const float* p = output + (size_t)(b * kCellsPerB + idx) * kChan;
    const float4 tv = *(const float4*)p;  // t0..t3 (85-float stride keeps
    const float t4 = p[4];                //  16B alignment: 85*4 % 16 != 0 is
    const float t0 = tv.x, t1 = tv.y, t2 = tv.z, t3 = tv.w;  // fine, see note
    const float aw = sanch[2 * a], ah = sanch[2 * a + 1];

    const float sx = 1.0f / (1.0f + expf(-t0));
    const float sy = 1.0f / (1.0f + expf(-t1));
    const float cx = (sx + (float)gx) * (1.0f / (float)kW);
    const float cy = (sy + (float)gy) * (1.0f / (float)kH);
    const float pw = expf(t2) * aw;
    const float ph = expf(t3) * ah;
    const float px1 = cx - pw * 0.5f, px2 = cx + pw * 0.5f;
    const float py1 = cy - ph * 0.5f, py2 = cy + ph * 0.5f;
    const float parea = (px2 - px1) * (py2 - py1);

    // fused: noobj candidacy (max IoU < 0.6  <=>  all inter < 0.6*union)
    //      + winner scan (key match, max anchor-iou, first-t tiebreak)
    bool okno = true;
    int bt = -1;
    float bi = 0.0f;  // init 0 enforces reference's iou > 0 win condition
    for (int t = 0; t < kT; ++t) {
      const float4 bx = sbox[t];
      const float4 mt = smeta[t];
      const float xm = fmaxf(px1, bx.x), xM = fminf(px2, bx.z);
      const float ym = fmaxf(py1, bx.y), yM = fminf(py2, bx.w);
      const float inter = fmaxf(xM - xm, 0.0f) * fmaxf(yM - ym, 0.0f);
      const float uni = fmaxf(parea + mt.x - inter, 1e-12f);
      okno = okno && (inter < kThresh * uni);
      if (__float_as_int(mt.z) == idx && mt.y > bi) { bi = mt.y; bt = t; }
    }

    if (priorOn) {
      const float dw = pw - aw, dh = ph - ah;
      contrib += dw * dw + dh * dh;  // PRIOR_RATE = 1
    }

    if (bt >= 0) {
      const float4 tg = stgt[bt];
      const float2 fc = sfxc[bt];
      const float d0 = t0 - tg.x, d1 = t1 - tg.y;
      const float d2 = t2 - tg.z, d3 = t3 - tg.w;
      contrib += fc.x * (d0 * d0 + d1 * d1 + d2 * d2 + d3 * d3);  // COORD
      const float dob = t4 - bi;
      contrib += 5.0f * dob * dob;                                // OBJECT
      const int cls = __float_as_int(fc.y);
      float cs = 0.0f;
      for (int c = 0; c < kC; ++c) {
        const float d = p[5 + c] - ((c == cls) ? 1.0f : 0.0f);
        cs += d * d;
      }
      contrib += cs;                                              // CLASS
    } else if (okno) {
      contrib += t4 * t4;                                         // NOOBJ
    }
  }

  // deterministic block reduction
  for (int off = 32; off > 0; off >>= 1) contrib += __shfl_down(contrib, off);
  const int lane = threadIdx.x & 63;
  const int wid = threadIdx.x >> 6;
  if (lane == 0) wsum[wid] = contrib;
  __syncthreads();
  if (threadIdx.x == 0) {
    partial[b * kMainBlocks + blockIdx.x] = wsum[0] + wsum[1] + wsum[2] + wsum[3];
  }
}

// Final deterministic reduction of the 928 block partials.
__global__ __launch_bounds__(256) void yolo_reduce_kernel(
    const float* __restrict__ partial, float* __restrict__ out) {
  __shared__ float s[256];
  float v = 0.0f;
  for (int i = threadIdx.x; i < kNPart; i += 256) v += partial[i];
  s[threadIdx.x] = v;
  __syncthreads();
  for (int off = 128; off > 0; off >>= 1) {
    if (threadIdx.x < off) s[threadIdx.x] += s[threadIdx.x + off];
    __syncthreads();
  }
  if (threadIdx.x == 0) out[0] = s[0] * (1.0f / (float)kB);
}

extern "C" void kernel_launch(void* const* d_in, const int* in_sizes, int n_in,
                              void* d_out, int out_size, void* d_ws, size_t ws_size,
                              hipStream_t stream) {
  const float* output  = (const float*)d_in[0];
  const float* truths  = (const float*)d_in[1];
  const float* anchors = (const float*)d_in[2];
  const int*   iter_p  = (const int*)d_in[3];
  float* out = (float*)d_out;
  float* partial = (float*)d_ws;  // kNPart floats

  hipLaunchKernelGGL(yolo_main_kernel, dim3(kMainBlocks, kB), dim3(256), 0,
                     stream, output, truths, anchors, iter_p, partial);
  hipLaunchKernelGGL(yolo_reduce_kernel, dim3(1), dim3(256), 0,
                     stream, partial, out);
}

// Round 4
// 22.437 us; speedup vs baseline: 6.6280x; 1.0141x over previous
//
#include <hip/hip_runtime.h>
#include <math.h>

namespace {
constexpr int kB = 32;
constexpr int kH = 38;
constexpr int kW = 38;
constexpr int kA = 5;
constexpr int kC = 80;
constexpr int kT = 60;
constexpr int kHW = kH * kW;                           // 1444
constexpr int kCellsPerB = kHW * kA;                   // 7220
constexpr int kChan = 5 + kC;                          // 85
constexpr int kMainBlocks = (kCellsPerB + 255) / 256;  // 29
constexpr int kNPart = kMainBlocks * kB;               // 928
constexpr int kPriorIter = 12800;
// inter/union < 0.6  <=>  inter < 0.375*(parea+tarea)   (union clip at 1e-12
// is never active here: tarea >= 4e-4)
constexpr float kQ = 0.6f / 1.6f;  // 0.375
}

// Main kernel: staging threads precompute per-truth targets AND scatter the
// winner claim into a per-block LDS table (64-bit ds atomicMax, commutative
// -> deterministic). Cell threads: 60-iter division-free noobj loop, table
// lookup for responsibility, algebraic class sum. Block tree-reduce.
__global__ __launch_bounds__(256) void yolo_main_kernel(
    const float* __restrict__ output,
    const float* __restrict__ truths,
    const float* __restrict__ anchors,
    const int* __restrict__ iter_p,
    float* __restrict__ partial) {
  const int b = blockIdx.y;
  const int base = blockIdx.x * 256;         // first cell of this block
  const int idx = base + threadIdx.x;        // cell index within batch

  __shared__ float4 sbox[kT];                // x1,y1,x2,y2
  __shared__ float4 stgt[kT];                // ddx, ddy, wh0, wh1
  __shared__ float2 sfxc[kT];                // fix^2, cls(bitcast int)
  __shared__ unsigned long long swin[256];   // winner claims for this block
  __shared__ float sanch[2 * kA];
  __shared__ float wsum[4];

  swin[threadIdx.x] = 0ULL;
  if (threadIdx.x < 2 * kA) sanch[threadIdx.x] = anchors[threadIdx.x];
  __syncthreads();

  if (threadIdx.x < kT) {
    const int t = threadIdx.x;
    const float* tr = truths + (size_t)(b * kT + t) * 5;
    const float x1 = tr[0], y1 = tr[1], x2 = tr[2], y2 = tr[3], cls = tr[4];
    const float tw = x2 - x1, th = y2 - y1, tarea = tw * th;
    sbox[t] = make_float4(x1, y1, x2, y2);
    const float tdx = (x1 + x2) * 0.5f * (float)kW;
    const float tdy = (y1 + y2) * 0.5f * (float)kH;
    const float cxf = ceilf(tdx), cyf = ceilf(tdy);
    int gxi = (int)cxf - 1, gyi = (int)cyf - 1;
    gxi = min(max(gxi, 0), kW - 1);
    gyi = min(max(gyi, 0), kH - 1);
    // best anchor by truth-vs-anchor IoU (argmax, first on ties via strict >)
    float best = -1.0f;
    int ba = 0;
    for (int a2 = 0; a2 < kA; ++a2) {
      const float aw = anchors[2 * a2], ah = anchors[2 * a2 + 1];
      const float inter = fminf(tw, aw) * fminf(th, ah);
      const float uni = fmaxf(tarea + aw * ah - inter, 1e-12f);
      const float iou = inter / uni;
      if (iou > best) { best = iou; ba = a2; }
    }
    const int key = (gyi * kW + gxi) * kA + ba;
    const int local = key - base;
    if (local >= 0 && local < 256 && best > 0.0f) {
      // pack (iou, smallest-t-wins) -> max == reference's segment_max +
      // first-order tiebreak; iou>0 guard == reference's iouf>0
      const unsigned long long pk =
          ((unsigned long long)__float_as_uint(best) << 32) |
          (unsigned long long)(0xFFFFFFFFu - (unsigned int)t);
      atomicMax(&swin[local], pk);
    }
    const float fxr = tdx - (cxf - 1.0f);
    const float fyr = tdy - (cyf - 1.0f);
    stgt[t] = make_float4(-logf(1.0f / fxr - 1.0f),
                          -logf(1.0f / fyr - 1.0f),
                          logf(tw) / anchors[2 * ba],
                          logf(th) / anchors[2 * ba + 1]);
    sfxc[t] = make_float2(2.0f - tarea, __int_as_float((int)cls));
  }
  __syncthreads();

  const bool priorOn = (*iter_p < kPriorIter);
  float contrib = 0.0f;

  if (idx < kCellsPerB) {
    const int hw = idx / kA;
    const int a = idx - hw * kA;
    const int gx = hw % kW;
    const int gy = hw / kW;
    const float* p = output + (size_t)(b * kCellsPerB + idx) * kChan;
    const float4 tv = *(const float4*)p;  // t0..t3 (4B-aligned dwordx4: ok)
    const float t4 = p[4];
    const float t0 = tv.x, t1 = tv.y, t2 = tv.z, t3 = tv.w;
    const float aw = sanch[2 * a], ah = sanch[2 * a + 1];

    const float sx = __builtin_amdgcn_rcpf(1.0f + __expf(-t0));
    const float sy = __builtin_amdgcn_rcpf(1.0f + __expf(-t1));
    const float cx = (sx + (float)gx) * (1.0f / (float)kW);
    const float cy = (sy + (float)gy) * (1.0f / (float)kH);
    const float pw = __expf(t2) * aw;
    const float ph = __expf(t3) * ah;
    const float px1 = cx - pw * 0.5f, px2 = cx + pw * 0.5f;
    const float py1 = cy - ph * 0.5f, py2 = cy + ph * 0.5f;
    const float c0 = kQ * ((px2 - px1) * (py2 - py1));  // 0.375*parea

    // noobj candidacy: max IoU < 0.6  <=>  all (inter - 0.375*(parea+tarea)) < 0
    float mviol = -1.0f;
    for (int t = 0; t < kT; ++t) {
      const float4 bx = sbox[t];
      const float xm = fmaxf(px1, bx.x), xM = fminf(px2, bx.z);
      const float ym = fmaxf(py1, bx.y), yM = fminf(py2, bx.w);
      const float inter = fmaxf(xM - xm, 0.0f) * fmaxf(yM - ym, 0.0f);
      const float tarea = (bx.z - bx.x) * (bx.w - bx.y);
      mviol = fmaxf(mviol, inter - fmaf(kQ, tarea, c0));
    }

    if (priorOn) {
      const float dw = pw - aw, dh = ph - ah;
      contrib += dw * dw + dh * dh;  // PRIOR_RATE = 1
    }

    const unsigned long long pk = swin[threadIdx.x];
    if (pk != 0ULL) {
      const int t = (int)(0xFFFFFFFFu - (unsigned int)(pk & 0xFFFFFFFFULL));
      const float bi = __uint_as_float((unsigned int)(pk >> 32));
      const float4 tg = stgt[t];
      const float2 fc = sfxc[t];
      const float d0 = t0 - tg.x, d1 = t1 - tg.y;
      const float d2 = t2 - tg.z, d3 = t3 - tg.w;
      contrib += fc.x * (d0 * d0 + d1 * d1 + d2 * d2 + d3 * d3);  // COORD
      const float dob = t4 - bi;
      contrib += 5.0f * dob * dob;                                // OBJECT
      // CLASS: sum (pc - onehot)^2 = sum pc^2 - 2*p[cls] + 1
      const int cls = __float_as_int(fc.y);
      const float4* pc4 = (const float4*)(p + 5);
      float cs = 0.0f;
#pragma unroll
      for (int c = 0; c < kC / 4; ++c) {
        const float4 v = pc4[c];
        cs += v.x * v.x + v.y * v.y + v.z * v.z + v.w * v.w;
      }
      contrib += cs + 1.0f - 2.0f * p[5 + cls];
    } else if (mviol < 0.0f) {
      contrib += t4 * t4;                                         // NOOBJ
    }
  }

  // deterministic block reduction
  for (int off = 32; off > 0; off >>= 1) contrib += __shfl_down(contrib, off);
  const int lane = threadIdx.x & 63;
  const int wid = threadIdx.x >> 6;
  if (lane == 0) wsum[wid] = contrib;
  __syncthreads();
  if (threadIdx.x == 0) {
    partial[b * kMainBlocks + blockIdx.x] = wsum[0] + wsum[1] + wsum[2] + wsum[3];
  }
}

// Final deterministic reduction of the 928 block partials.
__global__ __launch_bounds__(256) void yolo_reduce_kernel(
    const float* __restrict__ partial, float* __restrict__ out) {
  __shared__ float s[256];
  float v = 0.0f;
  for (int i = threadIdx.x; i < kNPart; i += 256) v += partial[i];
  s[threadIdx.x] = v;
  __syncthreads();
  for (int off = 128; off > 0; off >>= 1) {
    if (threadIdx.x < off) s[threadIdx.x] += s[threadIdx.x + off];
    __syncthreads();
  }
  if (threadIdx.x == 0) out[0] = s[0] * (1.0f / (float)kB);
}

extern "C" void kernel_launch(void* const* d_in, const int* in_sizes, int n_in,
                              void* d_out, int out_size, void* d_ws, size_t ws_size,
                              hipStream_t stream) {
  const float* output  = (const float*)d_in[0];
  const float* truths  = (const float*)d_in[1];
  const float* anchors = (const float*)d_in[2];
  const int*   iter_p  = (const int*)d_in[3];
  float* out = (float*)d_out;
  float* partial = (float*)d_ws;  // kNPart floats

  hipLaunchKernelGGL(yolo_main_kernel, dim3(kMainBlocks, kB), dim3(256), 0,
                     stream, output, truths, anchors, iter_p, partial);
  hipLaunchKernelGGL(yolo_reduce_kernel, dim3(1), dim3(256), 0,
                     stream, partial, out);
}